// Round 4
// baseline (229.069 us; speedup 1.0000x reference)
//
#include <hip/hip_runtime.h>

#define BATCH 2
#define SS    256   // 16x16 subdomain grid
#define CC    128
#define HWN   256   // 16x16 spatial
#define FDIM  4096  // 64 ch * 8 * 8 per head

typedef unsigned int uint;
typedef unsigned short ushort;
typedef short bf16x8 __attribute__((ext_vector_type(8)));
typedef ushort us4 __attribute__((ext_vector_type(4)));
typedef float f32x4 __attribute__((ext_vector_type(4)));

__device__ __forceinline__ ushort f2b(float f) {
  uint u = __float_as_uint(f);
  return (ushort)((u + 0x7fffu + ((u >> 16) & 1u)) >> 16);  // RNE
}
__device__ __forceinline__ float b2f(ushort h) { return __uint_as_float((uint)h << 16); }

// ---------------- K1: qkv projection -----------------------------------------
// Grid: 512 blocks (one per bs), 512 threads = 8 waves.
// seq loaded with FULL-ROW coalesced float4s (1 KB/instruction), transposed
// into a 64 KB LDS tile sq[hw][c-pair] with slot XOR-swizzle:
//   byte(hw,c2) = hw*256 + (((c2>>2) ^ (hw&15) ^ ((hw>>4)&15))*16) + (c2&3)*4
// -> fragment ds_read_b128 conflict-free, staging writes ~4-way (free-ish).
// Wave wv owns output rows d = wv*16..+15 (mt8 = wv) for ALL hw and all qkvi;
// weight fragments come straight from global (L2-hot), so no weight LDS and
// only ONE barrier in the whole kernel. 64 KB LDS -> 2 blocks/CU, 16 waves/CU.
// Store layout unchanged: qkvh[(qkvi*16+b*8+n)][s][f'].
__global__ __launch_bounds__(512, 4) void k_qkv(const float* __restrict__ seq,
                                                const float* __restrict__ wqkv,
                                                ushort* __restrict__ qkvh,
                                                float* __restrict__ attn) {
  __shared__ ushort sq[256 * 128];   // 64 KB
  const int bs = blockIdx.x;
  const int b = bs >> 8, s = bs & 255;
  const int t = threadIdx.x;
  const int wv = t >> 6, lane = t & 63;
  const int qq = lane >> 4, m = lane & 15;

  // zero the attn accumulator (k_scores atomically adds into it)
  if (blockIdx.x < 36) {
    attn[blockIdx.x * 1024 + t] = 0.f;
    attn[blockIdx.x * 1024 + 512 + t] = 0.f;
  }

  // ---- weight fragments: afrag[qkvi][ks] j = bf16(W[qkvi*128+wv*16+m][ks*32+qq*8+j])
  bf16x8 afrag[3][4];
  #pragma unroll
  for (int qkvi = 0; qkvi < 3; ++qkvi)
    #pragma unroll
    for (int ks = 0; ks < 4; ++ks) {
      const float* wp = wqkv + (size_t)(qkvi * 128 + wv * 16 + m) * 128 + ks * 32 + qq * 8;
      f32x4 w0 = *(const f32x4*)(wp);
      f32x4 w1 = *(const f32x4*)(wp + 4);
      bf16x8 fr;
      #pragma unroll
      for (int e = 0; e < 4; ++e) { fr[e] = (short)f2b(w0[e]); fr[4 + e] = (short)f2b(w1[e]); }
      afrag[qkvi][ks] = fr;
    }

  // ---- stage seq -> LDS (transpose + bf16) ----
  const float* sp = seq + (size_t)bs * (CC * HWN);
  #pragma unroll
  for (int i = 0; i < 8; ++i) {
    const int c2 = i * 8 + wv;          // c rows 2*c2, 2*c2+1
    const int hw0 = lane * 4;
    f32x4 va = *(const f32x4*)(sp + (size_t)(2 * c2) * HWN + hw0);
    f32x4 vb = *(const f32x4*)(sp + (size_t)(2 * c2 + 1) * HWN + hw0);
    #pragma unroll
    for (int j = 0; j < 4; ++j) {
      const int hw = hw0 + j;
      const uint w = (uint)f2b(va[j]) | ((uint)f2b(vb[j]) << 16);
      const int slot = (c2 >> 2) ^ (hw & 15) ^ ((hw >> 4) & 15);
      *(uint*)((char*)sq + hw * 256 + slot * 16 + (c2 & 3) * 4) = w;
    }
  }
  __syncthreads();

  // ---- compute ----
  const int ch = wv >> 2, m4 = wv & 3;
  #pragma unroll 2
  for (int ntg = 0; ntg < 16; ++ntg) {
    const int hw = ntg * 16 + m;
    bf16x8 bfr[4];
    #pragma unroll
    for (int ks = 0; ks < 4; ++ks) {
      const int slot = (ks * 4 + qq) ^ m ^ ntg;   // (hw&15)=m, (hw>>4)=ntg
      bfr[ks] = *(const bf16x8*)((const char*)sq + hw * 256 + slot * 16);
    }
    const int n_qk = ((ntg >> 3) * 2 + (m >> 3)) * 2;
    const int hwl  = (ntg & 7) * 8 + (m & 7);
    const uint obase = (uint)(((b * 8 + n_qk) * SS + s) * FDIM + hwl * 16 + qq * 4);
    #pragma unroll
    for (int qkvi = 0; qkvi < 3; ++qkvi) {
      f32x4 acc = {0.f, 0.f, 0.f, 0.f};
      #pragma unroll
      for (int ks = 0; ks < 4; ++ks)
        acc = __builtin_amdgcn_mfma_f32_16x16x32_bf16(afrag[qkvi][ks], bfr[ks], acc, 0, 0, 0);
      us4 pk;
      #pragma unroll
      for (int r = 0; r < 4; ++r) pk[r] = f2b(acc[r]);
      *(us4*)(qkvh + obase + (uint)((qkvi * 16 + ch) * (SS * FDIM) + m4 * 1024)) = pk;
    }
  }
}

// ---------------- K2: MFMA scores -> banded atomic partials ------------------
// Barrier-free: 1024 blocks x 4 independent waves. Wave = (b,n,sy,chunk):
// 256-elem slice of FDIM, 24 MFMAs, then <=12 masked f32 atomicAdds into
// attn[unit][s][9] (pre-zeroed by k_qkv). No LDS, no convoy, no serial tail.
// XCD swizzle: each XCD owns 2 whole (b,n) slices.
__global__ __launch_bounds__(256) void k_scores(const ushort* __restrict__ qkvh,
                                                float* __restrict__ attn) {
  const int g = blockIdx.x;
  const int unit = (g & 7) * 128 + (g >> 3);   // bijective (1024 % 8 == 0)
  const int cg = unit & 3;
  const int sy = (unit >> 2) & 15;
  const int bn = unit >> 6;                    // b*8+n
  const int t = threadIdx.x;
  const int wave = t >> 6, lane = t & 63;
  const int qq = lane >> 4, l15 = lane & 15;
  const size_t hs = (size_t)SS * FDIM;
  const ushort* qb = qkvh + (size_t)bn * hs;
  const ushort* kb = qkvh + (size_t)(16 + bn) * hs;

  const ushort* qp = qb + (size_t)(sy * 16 + l15) * FDIM + qq * 8;
  const ushort* kp[3];
  #pragma unroll
  for (int tl = 0; tl < 3; ++tl) {
    const int tyc = min(max(sy - 1 + tl, 0), 15);
    kp[tl] = kb + (size_t)(tyc * 16 + l15) * FDIM + qq * 8;
  }

  f32x4 acc[3] = {{0,0,0,0},{0,0,0,0},{0,0,0,0}};
  const int kbeg = (cg * 4 + wave) * 256;      // chunk of 256 k-elems
  #pragma unroll
  for (int it = 0; it < 4; ++it) {
    const int k0 = kbeg + it * 64;
    bf16x8 a0 = *(const bf16x8*)(qp + k0);
    bf16x8 a1 = *(const bf16x8*)(qp + k0 + 32);
    bf16x8 b0[3], b1[3];
    #pragma unroll
    for (int tl = 0; tl < 3; ++tl) {
      b0[tl] = *(const bf16x8*)(kp[tl] + k0);
      b1[tl] = *(const bf16x8*)(kp[tl] + k0 + 32);
    }
    #pragma unroll
    for (int tl = 0; tl < 3; ++tl)
      acc[tl] = __builtin_amdgcn_mfma_f32_16x16x32_bf16(a0, b0[tl], acc[tl], 0, 0, 0);
    #pragma unroll
    for (int tl = 0; tl < 3; ++tl)
      acc[tl] = __builtin_amdgcn_mfma_f32_16x16x32_bf16(a1, b1[tl], acc[tl], 0, 0, 0);
  }

  // D layout: row sx = qq*4+r, col tx = l15. Band: |tx-sx|<=1, ty in range.
  const int tx = l15;
  #pragma unroll
  for (int tl = 0; tl < 3; ++tl) {
    const int ty = sy - 1 + tl;
    if (ty < 0 || ty > 15) continue;           // wave-uniform
    #pragma unroll
    for (int r = 0; r < 4; ++r) {
      const int sx = qq * 4 + r;
      const int dx = tx - sx + 1;
      if (dx >= 0 && dx <= 2)
        atomicAdd(&attn[((size_t)bn * SS + sy * 16 + sx) * 9 + tl * 3 + dx], acc[tl][r]);
    }
  }
}

// ---------------- K2b: mask + softmax in place on attn -----------------------
__global__ __launch_bounds__(256) void k_softmax(float* __restrict__ attn) {
  const int id = blockIdx.x * 256 + threadIdx.x;  // 4096 = 16 units x 256 s
  const int s = id & 255, sy = s >> 4, sx = s & 15;
  float* ap = attn + (size_t)id * 9;
  float v[9];
  bool vld[9];
  #pragma unroll
  for (int j = 0; j < 9; ++j) {
    v[j] = ap[j];
    const int ny = sy + j / 3 - 1, nx = sx + j % 3 - 1;
    vld[j] = (ny >= 0 && ny < 16 && nx >= 0 && nx < 16);
  }
  float mx = -1e30f;
  float sc[9];
  #pragma unroll
  for (int j = 0; j < 9; ++j) {
    sc[j] = vld[j] ? v[j] * (1.f / 64.f) : -1e30f;
    mx = fmaxf(mx, sc[j]);
  }
  float p[9], sum = 0.f;
  #pragma unroll
  for (int j = 0; j < 9; ++j) {
    p[j] = vld[j] ? __expf(sc[j] - mx) : 0.f;
    sum += p[j];
  }
  const float inv = 1.f / sum;
  #pragma unroll
  for (int j = 0; j < 9; ++j) ap[j] = p[j] * inv;
}

// ---------------- K3a: PV (9-point weighted V sum) ---------------------------
// Grid 4096: one block per (eta, s). Writes sa into the DEAD Q region of qkvh
// (slices 0..15) in V layout, NONTEMPORAL so the V band stays L2-resident.
__global__ __launch_bounds__(256) void k_pv(const ushort* __restrict__ qkvh,
                                            const float* __restrict__ attn,
                                            ushort* __restrict__ sa) {
  const int g = blockIdx.x;
  const int unit = (g & 7) * 512 + (g >> 3);   // bijective (4096 % 8 == 0)
  const int eta = unit >> 8, s = unit & 255;
  const int sy = s >> 4, sx = s & 15;
  const int t = threadIdx.x;
  const size_t hs = (size_t)SS * FDIM;

  float p[9];
  int sjc[9];
  bool vld[9];
  #pragma unroll
  for (int j = 0; j < 9; ++j) {
    const int ny = sy + j / 3 - 1, nx = sx + j % 3 - 1;
    vld[j] = (ny >= 0 && ny < 16 && nx >= 0 && nx < 16);
    sjc[j] = min(max(ny, 0), 15) * 16 + min(max(nx, 0), 15);
    p[j] = vld[j] ? attn[((size_t)eta * SS + s) * 9 + j] : 0.f;
  }

  const ushort* vb = qkvh + (size_t)(32 + eta) * hs;
  const int f0 = t * 16;
  float acc[16];
  #pragma unroll
  for (int e = 0; e < 16; ++e) acc[e] = 0.f;
  #pragma unroll
  for (int j = 0; j < 9; ++j) {
    if (vld[j]) {   // block-uniform branch
      const ushort* vp = vb + (size_t)sjc[j] * FDIM + f0;
      bf16x8 v0 = *(const bf16x8*)(vp);
      bf16x8 v1 = *(const bf16x8*)(vp + 8);
      const float pj = p[j];
      #pragma unroll
      for (int e = 0; e < 8; ++e) acc[e]     += pj * b2f((ushort)v0[e]);
      #pragma unroll
      for (int e = 0; e < 8; ++e) acc[8 + e] += pj * b2f((ushort)v1[e]);
    }
  }
  bf16x8 r0, r1;
  #pragma unroll
  for (int e = 0; e < 8; ++e) { r0[e] = (short)f2b(acc[e]); r1[e] = (short)f2b(acc[8 + e]); }
  ushort* op = sa + ((size_t)eta * SS + s) * FDIM + f0;
  __builtin_nontemporal_store(r0, (bf16x8*)op);
  __builtin_nontemporal_store(r1, (bf16x8*)(op + 8));
}

// ---------------- K3b: out projection (GEMM with staged wout) ----------------
__global__ __launch_bounds__(256) void k_proj(const ushort* __restrict__ qkvh,
                                              const float* __restrict__ wout,
                                              const float* __restrict__ bout,
                                              float* __restrict__ out) {
  __shared__ ushort wlds[128 * 128];   // 32 KB, XOR-swizzled
  const int g = blockIdx.x;
  const int r9 = g >> 3;
  const int G = (g & 7) * 4 + (r9 >> 6);      // (b,sy) region, 0..31
  const int idx = r9 & 63;                     // 16 sx x 4 sub
  const int b = G >> 4, sy = G & 15;
  const int sx = idx >> 2, sub = idx & 3;
  const int s = sy * 16 + sx;
  const int bs = b * 256 + s;
  const int t = threadIdx.x;
  const int wave = t >> 6, lane = t & 63;
  const int ntg = sub * 4 + wave;
  const int qq = lane >> 4, m = lane & 15;
  const size_t hs = (size_t)SS * FDIM;

  // Stage wout into LDS with the cc' permutation + f32->bf16 conversion.
  {
    const int col16 = t & 15;
    const int ks = col16 >> 2, qw = col16 & 3;
    const int creal0 = (ks >> 1) * 64 + ((((ks & 1) << 1) | (qw >> 1)) << 4)
                       + ((qw & 1) << 3);
    #pragma unroll
    for (int i = 0; i < 8; ++i) {
      const int row = i * 16 + (t >> 4);
      const float* wp = wout + (size_t)row * 128 + creal0;
      f32x4 w0 = *(const f32x4*)(wp);
      f32x4 w1 = *(const f32x4*)(wp + 4);
      bf16x8 fr;
      #pragma unroll
      for (int e = 0; e < 4; ++e) { fr[e] = (short)f2b(w0[e]); fr[4 + e] = (short)f2b(w1[e]); }
      *(bf16x8*)&wlds[row * 128 + ((col16 ^ (row & 15)) * 8)] = fr;
    }
  }

  const int nbase = ((ntg >> 3) * 2 + (m >> 3)) * 2;  // + ch
  const int hwl = (ntg & 7) * 8 + (m & 7);
  bf16x8 bfrag[4];
  #pragma unroll
  for (int ks = 0; ks < 4; ++ks) {
    const int ch = ks >> 1;
    const int c64hi = ((ks & 1) << 1) | (qq >> 1);
    const int half = qq & 1;
    const ushort* sb = qkvh + (size_t)(b * 8 + nbase + ch) * hs;  // sa (Q region)
    const int off = c64hi * 1024 + hwl * 16 + half * 8;
    bfrag[ks] = *(const bf16x8*)(sb + (size_t)s * FDIM + off);
  }

  __syncthreads();   // staging complete before afrag reads

  #pragma unroll
  for (int mt = 0; mt < 8; ++mt) {
    bf16x8 afrag[4];
    #pragma unroll
    for (int ks = 0; ks < 4; ++ks)
      afrag[ks] = *(const bf16x8*)&wlds[(mt * 16 + m) * 128 + (((ks * 4 + qq) ^ m) * 8)];
    f32x4 acc = {0.f, 0.f, 0.f, 0.f};
    #pragma unroll
    for (int ks = 0; ks < 4; ++ks)
      acc = __builtin_amdgcn_mfma_f32_16x16x32_bf16(afrag[ks], bfrag[ks], acc, 0, 0, 0);
    const int hw = ntg * 16 + m;
    #pragma unroll
    for (int r = 0; r < 4; ++r) {
      const int d = mt * 16 + qq * 4 + r;
      out[((size_t)bs * CC + d) * HWN + hw] = acc[r] + bout[d];
    }
  }
}

extern "C" void kernel_launch(void* const* d_in, const int* in_sizes, int n_in,
                              void* d_out, int out_size, void* d_ws, size_t ws_size,
                              hipStream_t stream) {
  const float* seq  = (const float*)d_in[0];
  const float* wqkv = (const float*)d_in[1];
  const float* wout = (const float*)d_in[2];
  const float* bout = (const float*)d_in[3];
  char* ws = (char*)d_ws;
  // ws layout (bytes): qkvh 100663296 | attn 147456   (proven-available size)
  ushort* qkvh = (ushort*)(ws);
  float*  attn = (float*)(ws + 100663296ull);
  float*  outp = (float*)d_out;

  hipLaunchKernelGGL(k_qkv,     dim3(512),  dim3(512), 0, stream, seq, wqkv, qkvh, attn);
  hipLaunchKernelGGL(k_scores,  dim3(1024), dim3(256), 0, stream, qkvh, attn);
  hipLaunchKernelGGL(k_softmax, dim3(16),   dim3(256), 0, stream, attn);
  hipLaunchKernelGGL(k_pv,      dim3(4096), dim3(256), 0, stream, qkvh, attn, qkvh /* sa */);
  hipLaunchKernelGGL(k_proj,    dim3(2048), dim3(256), 0, stream, qkvh, wout, bout, outp);
}

// Round 5
// 188.416 us; speedup vs baseline: 1.2158x; 1.2158x over previous
//
#include <hip/hip_runtime.h>

#define BATCH 2
#define SS    256   // 16x16 subdomain grid
#define CC    128
#define HWN   256   // 16x16 spatial
#define FDIM  4096  // 64 ch * 8 * 8 per head

typedef unsigned int uint;
typedef unsigned short ushort;
typedef short bf16x8 __attribute__((ext_vector_type(8)));
typedef ushort us4 __attribute__((ext_vector_type(4)));
typedef float f32x4 __attribute__((ext_vector_type(4)));

__device__ __forceinline__ ushort f2b(float f) {
  uint u = __float_as_uint(f);
  return (ushort)((u + 0x7fffu + ((u >> 16) & 1u)) >> 16);  // RNE
}
__device__ __forceinline__ float b2f(ushort h) { return __uint_as_float((uint)h << 16); }

// ---------------- K1: qkv projection (round-3 version, measured 48.5 us) -----
// Grid: 512 blocks (one per bs), 512 threads = 8 waves, each wave owns 2
// column sets (N=32). Weights converted f32->bf16 inline during staging.
// Store layout: qkvh[(qkvi*16+b*8+n)][s][f'], f' = (c>>4)*1024 + hwl*16 + (c&15)
__global__ __launch_bounds__(512, 4) void k_qkv(const float* __restrict__ seq,
                                                const float* __restrict__ wqkv,
                                                ushort* __restrict__ qkvh) {
  __shared__ ushort wlds[128 * 128];   // 32 KB, XOR-swizzled 16-B blocks
  const int bs = blockIdx.x;
  const int b = bs >> 8, s = bs & 255;
  const int t = threadIdx.x;
  const int wv = t >> 6, lane = t & 63;
  const int qq = lane >> 4, m = lane & 15;

  const float* sp = seq + (size_t)bs * (CC * HWN);

  bf16x8 bfrag[2][4];
  uint obase[2];
  #pragma unroll
  for (int set = 0; set < 2; ++set) {
    const int ntg = wv * 2 + set;
    const int hw = ntg * 16 + m;
    #pragma unroll
    for (int ks = 0; ks < 4; ++ks) {
      const int k0 = ks * 32 + qq * 8;
      float tmp[8];
      #pragma unroll
      for (int j = 0; j < 8; ++j) tmp[j] = sp[(k0 + j) * HWN + hw];
      bf16x8 fr;
      #pragma unroll
      for (int j = 0; j < 8; ++j) fr[j] = (short)f2b(tmp[j]);
      bfrag[set][ks] = fr;
    }
    const int n_qk = ((ntg >> 3) * 2 + (m >> 3)) * 2;
    const int hwl  = (ntg & 7) * 8 + (m & 7);
    obase[set] = (uint)(((b * 8 + n_qk) * SS + s) * FDIM + hwl * 16 + qq * 4);
  }

  for (int qkvi = 0; qkvi < 3; ++qkvi) {
    if (qkvi) __syncthreads();
    #pragma unroll
    for (int i = 0; i < 4; ++i) {
      const int row = i * 32 + (t >> 4), col16 = t & 15;
      const float* wp = wqkv + (size_t)(qkvi * 128 + row) * 128 + col16 * 8;
      f32x4 w0 = *(const f32x4*)(wp);
      f32x4 w1 = *(const f32x4*)(wp + 4);
      bf16x8 fr;
      #pragma unroll
      for (int e = 0; e < 4; ++e) { fr[e] = (short)f2b(w0[e]); fr[4 + e] = (short)f2b(w1[e]); }
      *(bf16x8*)&wlds[row * 128 + ((col16 ^ (row & 15)) * 8)] = fr;
    }
    __syncthreads();

    #pragma unroll
    for (int mt8 = 0; mt8 < 8; ++mt8) {
      bf16x8 afrag[4];
      #pragma unroll
      for (int ks = 0; ks < 4; ++ks)
        afrag[ks] = *(const bf16x8*)&wlds[(mt8 * 16 + m) * 128 + (((ks * 4 + qq) ^ m) * 8)];
      const int ch = mt8 >> 2, m4 = mt8 & 3;
      #pragma unroll
      for (int set = 0; set < 2; ++set) {
        f32x4 acc = {0.f, 0.f, 0.f, 0.f};
        #pragma unroll
        for (int ks = 0; ks < 4; ++ks)
          acc = __builtin_amdgcn_mfma_f32_16x16x32_bf16(afrag[ks], bfrag[set][ks], acc, 0, 0, 0);
        us4 pk;
        #pragma unroll
        for (int r = 0; r < 4; ++r) pk[r] = f2b(acc[r]);
        *(us4*)(qkvh + obase[set]
                + (uint)((qkvi * 16 + ch) * (SS * FDIM) + m4 * 1024)) = pk;
      }
    }
  }
}

// ---------------- K2: MFMA scores + softmax (round-0 convoy version) ---------
__global__ __launch_bounds__(1024) void k_scores(const ushort* __restrict__ qkvh,
                                                 float* __restrict__ attn) {
  __shared__ float red[16][64][12];
  const int g = blockIdx.x;
  const int unit = (g & 7) * 32 + (g >> 3);   // XCD swizzle
  const int b  = unit >> 7;
  const int n  = (unit >> 4) & 7;
  const int sy = unit & 15;
  const int t = threadIdx.x;
  const int wave = t >> 6, lane = t & 63;
  const int qq = lane >> 4, l15 = lane & 15;
  const size_t hs = (size_t)SS * FDIM;
  const ushort* qb = qkvh + (size_t)(b * 8 + n) * hs;
  const ushort* kb = qkvh + (size_t)(16 + b * 8 + n) * hs;

  const ushort* qp = qb + (size_t)(sy * 16 + l15) * FDIM + qq * 8;
  const ushort* kp[3];
  #pragma unroll
  for (int tl = 0; tl < 3; ++tl) {
    const int tyc = min(max(sy - 1 + tl, 0), 15);
    kp[tl] = kb + (size_t)(tyc * 16 + l15) * FDIM + qq * 8;
  }

  f32x4 acc[3] = {{0,0,0,0},{0,0,0,0},{0,0,0,0}};
  const int kbeg = wave * 256;
  #pragma unroll
  for (int it = 0; it < 4; ++it) {
    const int k0 = kbeg + it * 64;
    bf16x8 a0 = *(const bf16x8*)(qp + k0);
    bf16x8 a1 = *(const bf16x8*)(qp + k0 + 32);
    bf16x8 b0[3], b1[3];
    #pragma unroll
    for (int tl = 0; tl < 3; ++tl) {
      b0[tl] = *(const bf16x8*)(kp[tl] + k0);
      b1[tl] = *(const bf16x8*)(kp[tl] + k0 + 32);
    }
    #pragma unroll
    for (int tl = 0; tl < 3; ++tl)
      acc[tl] = __builtin_amdgcn_mfma_f32_16x16x32_bf16(a0, b0[tl], acc[tl], 0, 0, 0);
    #pragma unroll
    for (int tl = 0; tl < 3; ++tl)
      acc[tl] = __builtin_amdgcn_mfma_f32_16x16x32_bf16(a1, b1[tl], acc[tl], 0, 0, 0);
  }

  #pragma unroll
  for (int tl = 0; tl < 3; ++tl)
    #pragma unroll
    for (int r = 0; r < 4; ++r) red[wave][lane][tl * 4 + r] = acc[tl][r];
  __syncthreads();
  if (t < 768) {
    const int lane2 = t / 12, idx = t - lane2 * 12;
    float ssum = red[0][lane2][idx];
    #pragma unroll
    for (int w = 1; w < 16; ++w) ssum += red[w][lane2][idx];
    red[0][lane2][idx] = ssum;
  }
  __syncthreads();
  if (wave != 0) return;
  #pragma unroll
  for (int tl = 0; tl < 3; ++tl)
    #pragma unroll
    for (int r = 0; r < 4; ++r) acc[tl][r] = red[0][lane][tl * 4 + r];

  const int tx = l15;
  float sc[3][4];
  #pragma unroll
  for (int tl = 0; tl < 3; ++tl) {
    const int ty = sy - 1 + tl;
    const bool tyv = (ty >= 0 && ty < 16);
    #pragma unroll
    for (int r = 0; r < 4; ++r) {
      const int sx = qq * 4 + r;
      const bool v = tyv && (tx - sx <= 1) && (sx - tx <= 1);
      sc[tl][r] = v ? acc[tl][r] * (1.f / 64.f) : -1e30f;
    }
  }
  #pragma unroll
  for (int r = 0; r < 4; ++r) {
    float mx = fmaxf(fmaxf(sc[0][r], sc[1][r]), sc[2][r]);
    #pragma unroll
    for (int off = 1; off < 16; off <<= 1) mx = fmaxf(mx, __shfl_xor(mx, off));
    float p[3], sum = 0.f;
    #pragma unroll
    for (int tl = 0; tl < 3; ++tl) { p[tl] = __expf(sc[tl][r] - mx); sum += p[tl]; }
    #pragma unroll
    for (int off = 1; off < 16; off <<= 1) sum += __shfl_xor(sum, off);
    const float inv = 1.f / sum;
    const int sx = qq * 4 + r;
    const int s = sy * 16 + sx;
    #pragma unroll
    for (int tl = 0; tl < 3; ++tl) {
      const int ty = sy - 1 + tl;
      const int dxp = tx - sx + 1;
      if (ty >= 0 && ty < 16 && dxp >= 0 && dxp <= 2)
        attn[((size_t)(b * 8 + n) * SS + s) * 9 + tl * 3 + dxp] = p[tl] * inv;
    }
  }
}

// ---------------- K3: fused PV + out projection (round-0 version) ------------
// Grid 2048, 256 threads, N=16 per wave; wout staged inline (f32->bf16 with
// the cc' permutation, proven in round-3 k_proj). XCD swizzle: each XCD owns
// whole (b,sy) regions -> 3-row V working set stays in its L2.
__global__ __launch_bounds__(256) void k_out(const ushort* __restrict__ qkvh,
                                             const float* __restrict__ attn,
                                             const float* __restrict__ wout,
                                             const float* __restrict__ bout,
                                             float* __restrict__ out) {
  __shared__ ushort wlds[128 * 128];   // 32 KB, XOR-swizzled
  const int g = blockIdx.x;
  const int r9 = g >> 3;
  const int G = (g & 7) * 4 + (r9 >> 6);      // (b,sy) region, 0..31
  const int idx = r9 & 63;                     // 16 sx x 4 sub
  const int b = G >> 4, sy = G & 15;
  const int sx = idx >> 2, sub = idx & 3;
  const int s = sy * 16 + sx;
  const int bs = b * 256 + s;
  const int t = threadIdx.x;
  const int wave = t >> 6, lane = t & 63;
  const int ntg = sub * 4 + wave;
  const int qq = lane >> 4, m = lane & 15;
  const size_t hs = (size_t)SS * FDIM;

  // Stage wout into LDS with the cc' permutation + f32->bf16 conversion.
  {
    const int col16 = t & 15;
    const int ks = col16 >> 2, qw = col16 & 3;
    const int creal0 = (ks >> 1) * 64 + ((((ks & 1) << 1) | (qw >> 1)) << 4)
                       + ((qw & 1) << 3);
    #pragma unroll
    for (int i = 0; i < 8; ++i) {
      const int row = i * 16 + (t >> 4);
      const float* wp = wout + (size_t)row * 128 + creal0;
      f32x4 w0 = *(const f32x4*)(wp);
      f32x4 w1 = *(const f32x4*)(wp + 4);
      bf16x8 fr;
      #pragma unroll
      for (int e = 0; e < 4; ++e) { fr[e] = (short)f2b(w0[e]); fr[4 + e] = (short)f2b(w1[e]); }
      *(bf16x8*)&wlds[row * 128 + ((col16 ^ (row & 15)) * 8)] = fr;
    }
  }

  int sjc[9];
  bool vld[9];
  #pragma unroll
  for (int j = 0; j < 9; ++j) {
    const int ny = sy + j / 3 - 1, nx = sx + j % 3 - 1;
    vld[j] = (ny >= 0 && ny < 16 && nx >= 0 && nx < 16);
    sjc[j] = min(max(ny, 0), 15) * 16 + min(max(nx, 0), 15);
  }

  const int nbase = ((ntg >> 3) * 2 + (m >> 3)) * 2;  // + ch
  float pch[2][9];
  #pragma unroll
  for (int ch = 0; ch < 2; ++ch) {
    #pragma unroll
    for (int j = 0; j < 9; ++j) {
      const float w = attn[((size_t)(b * 8 + nbase + ch) * SS + s) * 9 + j];
      pch[ch][j] = vld[j] ? w : 0.f;
    }
  }

  // sa in MFMA B-fragment layout; unified v layout -> 4 x 256-B segments/load
  const int hwl = (ntg & 7) * 8 + (m & 7);
  bf16x8 bfrag[4];
  #pragma unroll
  for (int ks = 0; ks < 4; ++ks) {
    const int ch = ks >> 1;
    const int c64hi = ((ks & 1) << 1) | (qq >> 1);
    const int half = qq & 1;
    const ushort* vb = qkvh + (size_t)(32 + b * 8 + nbase + ch) * hs;
    const int off = c64hi * 1024 + hwl * 16 + half * 8;
    float facc[8] = {0.f, 0.f, 0.f, 0.f, 0.f, 0.f, 0.f, 0.f};
    #pragma unroll
    for (int j = 0; j < 9; ++j) {
      bf16x8 vv = *(const bf16x8*)(vb + (size_t)sjc[j] * FDIM + off);
      const float pj = pch[ch][j];
      #pragma unroll
      for (int e = 0; e < 8; ++e) facc[e] += pj * b2f((ushort)vv[e]);
    }
    bf16x8 fr;
    #pragma unroll
    for (int e = 0; e < 8; ++e) fr[e] = (short)f2b(facc[e]);
    bfrag[ks] = fr;
  }

  __syncthreads();   // staging complete before afrag reads

  // out[d][hw] = wout_perm[d][cc'] @ sa[cc'][hw] + bout[d]
  #pragma unroll
  for (int mt = 0; mt < 8; ++mt) {
    bf16x8 afrag[4];
    #pragma unroll
    for (int ks = 0; ks < 4; ++ks)
      afrag[ks] = *(const bf16x8*)&wlds[(mt * 16 + m) * 128 + (((ks * 4 + qq) ^ m) * 8)];
    f32x4 acc = {0.f, 0.f, 0.f, 0.f};
    #pragma unroll
    for (int ks = 0; ks < 4; ++ks)
      acc = __builtin_amdgcn_mfma_f32_16x16x32_bf16(afrag[ks], bfrag[ks], acc, 0, 0, 0);
    const int hw = ntg * 16 + m;
    #pragma unroll
    for (int r = 0; r < 4; ++r) {
      const int d = mt * 16 + qq * 4 + r;
      out[((size_t)bs * CC + d) * HWN + hw] = acc[r] + bout[d];
    }
  }
}

extern "C" void kernel_launch(void* const* d_in, const int* in_sizes, int n_in,
                              void* d_out, int out_size, void* d_ws, size_t ws_size,
                              hipStream_t stream) {
  const float* seq  = (const float*)d_in[0];
  const float* wqkv = (const float*)d_in[1];
  const float* wout = (const float*)d_in[2];
  const float* bout = (const float*)d_in[3];
  char* ws = (char*)d_ws;
  // ws layout (bytes): qkvh 100663296 | attn 147456
  ushort* qkvh = (ushort*)(ws);
  float*  attn = (float*)(ws + 100663296ull);
  float*  outp = (float*)d_out;

  hipLaunchKernelGGL(k_qkv,    dim3(512),  dim3(512),  0, stream, seq, wqkv, qkvh);
  hipLaunchKernelGGL(k_scores, dim3(256),  dim3(1024), 0, stream, qkvh, attn);
  hipLaunchKernelGGL(k_out,    dim3(2048), dim3(256),  0, stream, qkvh, attn, wout, bout, outp);
}